// Round 1
// baseline (72.878 us; speedup 1.0000x reference)
//
#include <hip/hip_runtime.h>
#include <hip/hip_bf16.h>

#define HH 256
#define WW 256
#define NN 512
#define FXC 300.0f
#define FYC 300.0f
#define CXC 128.0f
#define CYC 128.0f
#define NEARC 0.01f
#define MAXRAD 20.0f

// Packed per-gaussian params (sorted back-to-front), 12 floats each:
// [0]=u [1]=v [2]=x0 [3]=x1 [4]=y0 [5]=y1 [6]=neg_inv_2sig2 [7]=op [8]=r [9]=g [10]=b [11]=pad
#define GP_STRIDE 12

__global__ __launch_bounds__(NN) void prep_kernel(
    const float* __restrict__ pos,      // 512x3
    const float* __restrict__ scl,      // 512x3
    const float* __restrict__ col,      // 512x3
    const float* __restrict__ opac,     // 512
    const float* __restrict__ viewm,    // 16
    float* __restrict__ gp)             // 512*12 out (sorted)
{
    __shared__ float sd[NN];
    __shared__ float sV[16];
    const int i = threadIdx.x;
    if (i < 16) sV[i] = viewm[i];
    __syncthreads();

    const float px = pos[i * 3 + 0];
    const float py = pos[i * 3 + 1];
    const float pz = pos[i * 3 + 2];

    const float cx = sV[0] * px + sV[1] * py + sV[2]  * pz + sV[3];
    const float cy = sV[4] * px + sV[5] * py + sV[6]  * pz + sV[7];
    const float cz = sV[8] * px + sV[9] * py + sV[10] * pz + sV[11];

    const float zs = cz + 1e-8f;
    const float sgn = (zs > 0.0f) ? 1.0f : ((zs < 0.0f) ? -1.0f : 0.0f);
    const float z2 = fmaxf(fabsf(cz), NEARC) * sgn;
    const float d = -z2;                    // depth

    sd[i] = d;
    __syncthreads();

    // stable rank for descending-depth order (== jnp.argsort(-depths))
    int rank = 0;
    const float di = d;
    for (int j = 0; j < NN; ++j) {
        const float dj = sd[j];
        rank += (dj > di) | ((dj == di) & (j < i));
    }

    float u = 0.0f, v = 0.0f;
    float x0 = 1e9f, x1 = -1e9f, y0 = 1e9f, y1 = -1e9f;
    float neg_inv = 0.0f;
    if (d > 0.0f) {
        u = FXC * cx / d + CXC;
        v = CYC - FYC * cy / d;
        const float sm = (scl[i * 3 + 0] + scl[i * 3 + 1] + scl[i * 3 + 2]) * (1.0f / 3.0f);
        float radius = floorf(sm * FXC / d);
        radius = fminf(fmaxf(radius, 1.0f), MAXRAD);
        const float xi = truncf(u);
        const float yi = truncf(v);
        x0 = fmaxf(0.0f, xi - radius);
        x1 = fminf((float)WW, xi + radius + 1.0f);
        y0 = fmaxf(0.0f, yi - radius);
        y1 = fminf((float)HH, yi + radius + 1.0f);
        const float sigma = fmaxf(radius * 0.5f, 1.0f);
        neg_inv = -1.0f / (2.0f * sigma * sigma);
    }

    float* o = gp + rank * GP_STRIDE;
    o[0]  = u;
    o[1]  = v;
    o[2]  = x0;
    o[3]  = x1;
    o[4]  = y0;
    o[5]  = y1;
    o[6]  = neg_inv;
    o[7]  = opac[i];
    o[8]  = col[i * 3 + 0];
    o[9]  = col[i * 3 + 1];
    o[10] = col[i * 3 + 2];
    o[11] = 0.0f;
}

__global__ __launch_bounds__(WW) void render_kernel(
    const float* __restrict__ gp,       // 512*12 sorted
    const float* __restrict__ bg,       // 3
    float* __restrict__ out)            // 3*256*256
{
    __shared__ float sg[NN * GP_STRIDE];

    // cooperative LDS fill: 6144 floats = 1536 float4, 256 threads -> 6 each
    {
        const float4* src = (const float4*)gp;
        float4* dst = (float4*)sg;
        #pragma unroll
        for (int k = 0; k < (NN * GP_STRIDE / 4) / WW; ++k)
            dst[k * WW + threadIdx.x] = src[k * WW + threadIdx.x];
    }
    __syncthreads();

    const int x = threadIdx.x;
    const int y = blockIdx.x;
    const float xx = (float)x;
    const float yy = (float)y;

    float cr = bg[0];
    float cg = bg[1];
    float cb = bg[2];

    for (int i = 0; i < NN; ++i) {
        const float* p = &sg[i * GP_STRIDE];
        const float y0 = p[4];
        const float y1 = p[5];
        // yy is uniform across the block -> wave-uniform skip
        if (yy < y0 || yy >= y1) continue;

        float a = 0.0f;
        const float x0 = p[2];
        const float x1 = p[3];
        if (xx >= x0 && xx < x1) {
            const float dx = xx - p[0];
            const float dy = yy - p[1];
            const float ds = dx * dx + dy * dy;
            a = __expf(ds * p[6]) * p[7];
            a = fminf(fmaxf(a, 0.0f), 1.0f);
        }
        const float one_m = 1.0f - a;
        cr = a * p[8]  + one_m * cr;
        cg = a * p[9]  + one_m * cg;
        cb = a * p[10] + one_m * cb;
    }

    const int pix = y * WW + x;
    out[0 * HH * WW + pix] = cr;
    out[1 * HH * WW + pix] = cg;
    out[2 * HH * WW + pix] = cb;
}

extern "C" void kernel_launch(void* const* d_in, const int* in_sizes, int n_in,
                              void* d_out, int out_size, void* d_ws, size_t ws_size,
                              hipStream_t stream) {
    const float* positions  = (const float*)d_in[0];
    const float* scales     = (const float*)d_in[1];
    // d_in[2] = rotations (unused by reference)
    const float* colors     = (const float*)d_in[3];
    const float* opacities  = (const float*)d_in[4];
    const float* view_matrix= (const float*)d_in[5];
    const float* background = (const float*)d_in[6];

    float* gp  = (float*)d_ws;              // 512*12 floats = 24 KB
    float* out = (float*)d_out;

    prep_kernel<<<1, NN, 0, stream>>>(positions, scales, colors, opacities, view_matrix, gp);
    render_kernel<<<HH, WW, 0, stream>>>(gp, background, out);
}

// Round 2
// 23.518 us; speedup vs baseline: 3.0988x; 3.0988x over previous
//
#include <hip/hip_runtime.h>
#include <hip/hip_bf16.h>

#define HH 256
#define WW 256
#define NN 512
#define FXC 300.0f
#define FYC 300.0f
#define CXC 128.0f
#define CYC 128.0f
#define NEARC 0.01f
#define MAXRAD 20.0f

// Packed per-gaussian params (sorted back-to-front), 12 floats each:
// [0]=u [1]=v [2]=x0 [3]=x1 [4]=y0 [5]=y1 [6]=neg_inv_2sig2 [7]=op [8]=r [9]=g [10]=b [11]=pad
#define GP_STRIDE 12

__global__ __launch_bounds__(NN) void prep_kernel(
    const float* __restrict__ pos,      // 512x3
    const float* __restrict__ scl,      // 512x3
    const float* __restrict__ col,      // 512x3
    const float* __restrict__ opac,     // 512
    const float* __restrict__ viewm,    // 16
    float* __restrict__ gp)             // 512*12 out (sorted)
{
    __shared__ float sd[NN];
    __shared__ float sV[16];
    const int i = threadIdx.x;
    if (i < 16) sV[i] = viewm[i];
    __syncthreads();

    const float px = pos[i * 3 + 0];
    const float py = pos[i * 3 + 1];
    const float pz = pos[i * 3 + 2];

    const float cx = sV[0] * px + sV[1] * py + sV[2]  * pz + sV[3];
    const float cy = sV[4] * px + sV[5] * py + sV[6]  * pz + sV[7];
    const float cz = sV[8] * px + sV[9] * py + sV[10] * pz + sV[11];

    const float zs = cz + 1e-8f;
    const float sgn = (zs > 0.0f) ? 1.0f : ((zs < 0.0f) ? -1.0f : 0.0f);
    const float z2 = fmaxf(fabsf(cz), NEARC) * sgn;
    const float d = -z2;                    // depth

    sd[i] = d;
    __syncthreads();

    // stable rank for descending-depth order (== jnp.argsort(-depths)),
    // vectorized: float4 LDS reads, 4 compares per iteration
    int rank = 0;
    const float di = d;
    const float4* sd4 = (const float4*)sd;
    #pragma unroll 8
    for (int j4 = 0; j4 < NN / 4; ++j4) {
        const float4 q = sd4[j4];
        const int j = j4 * 4;
        rank += (q.x > di) | ((q.x == di) & (j     < i));
        rank += (q.y > di) | ((q.y == di) & (j + 1 < i));
        rank += (q.z > di) | ((q.z == di) & (j + 2 < i));
        rank += (q.w > di) | ((q.w == di) & (j + 3 < i));
    }

    float u = 0.0f, v = 0.0f;
    float x0 = 1e9f, x1 = -1e9f, y0 = 1e9f, y1 = -1e9f;
    float neg_inv = 0.0f;
    if (d > 0.0f) {
        u = FXC * cx / d + CXC;
        v = CYC - FYC * cy / d;
        const float sm = (scl[i * 3 + 0] + scl[i * 3 + 1] + scl[i * 3 + 2]) * (1.0f / 3.0f);
        float radius = floorf(sm * FXC / d);
        radius = fminf(fmaxf(radius, 1.0f), MAXRAD);
        const float xi = truncf(u);
        const float yi = truncf(v);
        x0 = fmaxf(0.0f, xi - radius);
        x1 = fminf((float)WW, xi + radius + 1.0f);
        y0 = fmaxf(0.0f, yi - radius);
        y1 = fminf((float)HH, yi + radius + 1.0f);
        const float sigma = fmaxf(radius * 0.5f, 1.0f);
        neg_inv = -1.0f / (2.0f * sigma * sigma);
    }

    float* o = gp + rank * GP_STRIDE;
    o[0]  = u;
    o[1]  = v;
    o[2]  = x0;
    o[3]  = x1;
    o[4]  = y0;
    o[5]  = y1;
    o[6]  = neg_inv;
    o[7]  = opac[i];
    o[8]  = col[i * 3 + 0];
    o[9]  = col[i * 3 + 1];
    o[10] = col[i * 3 + 2];
    o[11] = 0.0f;
}

__global__ __launch_bounds__(WW) void render_kernel(
    const float* __restrict__ gp,       // 512*12 sorted
    const float* __restrict__ bg,       // 3
    float* __restrict__ out)            // 3*256*256
{
    __shared__ float sg[NN * GP_STRIDE];   // compacted params (worst case all 512)
    __shared__ int   slist[NN];            // compacted gaussian indices (rank order)
    __shared__ int   swave[4];             // per-wave selected counts
    __shared__ int   sM;

    const int t = threadIdx.x;
    const int wave = t >> 6;
    const int lane = t & 63;
    const int y = blockIdx.x;
    const float yy = (float)y;

    // ---- Phase 1: order-preserving compaction of gaussians touching row y ----
    // wave w owns ranks [w*128, w*128+128): chunk A = first 64, chunk B = last 64
    const int ia = wave * 128 + lane;
    const int ib = ia + 64;
    const float y0a = gp[ia * GP_STRIDE + 4];
    const float y1a = gp[ia * GP_STRIDE + 5];
    const float y0b = gp[ib * GP_STRIDE + 4];
    const float y1b = gp[ib * GP_STRIDE + 5];
    const bool fa = (yy >= y0a) && (yy < y1a);
    const bool fb = (yy >= y0b) && (yy < y1b);
    const unsigned long long ba = __ballot(fa);
    const unsigned long long bb = __ballot(fb);
    const int ca = __popcll(ba);
    if (lane == 0) swave[wave] = ca + __popcll(bb);
    __syncthreads();
    int base = 0;
    #pragma unroll
    for (int w = 0; w < 4; ++w) base += (w < wave) ? swave[w] : 0;
    if (t == 0) sM = swave[0] + swave[1] + swave[2] + swave[3];
    const unsigned long long lmask = (lane == 63) ? ~0ull >> 1 : ((1ull << (lane & 63)) - 1ull);
    // (lane<64 always; (1ull<<lane)-1 is fine for lane<64 except shift-by-64 UB at lane=64 which can't happen)
    if (fa) slist[base + __popcll(ba & ((1ull << lane) - 1ull))] = ia;
    if (fb) slist[base + ca + __popcll(bb & ((1ull << lane) - 1ull))] = ib;
    (void)lmask;
    __syncthreads();
    const int M = sM;

    // ---- Phase 2: gather selected params into compact LDS (float4 granularity) ----
    for (int k = t; k < M * 3; k += WW) {
        const int gi = k / 3;
        const int q  = k - gi * 3;
        ((float4*)sg)[gi * 3 + q] = ((const float4*)gp)[slist[gi] * 3 + q];
    }
    __syncthreads();

    // ---- Phase 3: per-pixel ordered blend over M gaussians ----
    const int x = t;
    const float xx = (float)x;

    float cr = bg[0];
    float cg = bg[1];
    float cb = bg[2];

    for (int i = 0; i < M; ++i) {
        const float* p = &sg[i * GP_STRIDE];
        float a = 0.0f;
        const float x0 = p[2];
        const float x1 = p[3];
        if (xx >= x0 && xx < x1) {
            const float dx = xx - p[0];
            const float dy = yy - p[1];
            const float ds = dx * dx + dy * dy;
            a = __expf(ds * p[6]) * p[7];
            a = fminf(fmaxf(a, 0.0f), 1.0f);
        }
        const float one_m = 1.0f - a;
        cr = a * p[8]  + one_m * cr;
        cg = a * p[9]  + one_m * cg;
        cb = a * p[10] + one_m * cb;
    }

    const int pix = y * WW + x;
    out[0 * HH * WW + pix] = cr;
    out[1 * HH * WW + pix] = cg;
    out[2 * HH * WW + pix] = cb;
}

extern "C" void kernel_launch(void* const* d_in, const int* in_sizes, int n_in,
                              void* d_out, int out_size, void* d_ws, size_t ws_size,
                              hipStream_t stream) {
    const float* positions  = (const float*)d_in[0];
    const float* scales     = (const float*)d_in[1];
    // d_in[2] = rotations (unused by reference)
    const float* colors     = (const float*)d_in[3];
    const float* opacities  = (const float*)d_in[4];
    const float* view_matrix= (const float*)d_in[5];
    const float* background = (const float*)d_in[6];

    float* gp  = (float*)d_ws;              // 512*12 floats = 24 KB
    float* out = (float*)d_out;

    prep_kernel<<<1, NN, 0, stream>>>(positions, scales, colors, opacities, view_matrix, gp);
    render_kernel<<<HH, WW, 0, stream>>>(gp, background, out);
}